// Round 9
// baseline (232.492 us; speedup 1.0000x reference)
//
#include <hip/hip_runtime.h>
#include <hip/hip_bf16.h>
#include <math.h>

#define BATCH 4096
#define DIM   2048
#define INV_T 2.0f   // 1 / TEMPERATURE, TEMPERATURE = 0.5

#define BM 256
#define BN 256

typedef float floatx4 __attribute__((ext_vector_type(4)));
typedef int   intx4   __attribute__((ext_vector_type(4)));
typedef int   intx8   __attribute__((ext_vector_type(8)));

static __device__ __forceinline__ void gld_lds16(const void* g, void* l) {
  __builtin_amdgcn_global_load_lds(
      (const __attribute__((address_space(1))) void*)g,
      (__attribute__((address_space(3))) void*)l, 16, 0, 0);
}

static __device__ __forceinline__ intx8 comb8(intx4 lo, intx4 hi) {
  intx8 r;
  r[0] = lo[0]; r[1] = lo[1]; r[2] = lo[2]; r[3] = lo[3];
  r[4] = hi[0]; r[5] = hi[1]; r[6] = hi[2]; r[7] = hi[3];
  return r;
}

// ---------------------------------------------------------------------------
// Kernel 1: per-row log-softmax prep. Wave-per-row, NO barriers.
// R13: Qb8 back to ROW-MAJOR (B is LDS-staged again in gemm; this is the
// harness-verified R5-R9 path). Small VALU cut: reuse e = exp(v-m) from the
// sum pass so j-rows do one transcendental pass, not two.
// ---------------------------------------------------------------------------
__global__ __launch_bounds__(256) void prep_kernel(
    const float* __restrict__ ci, const float* __restrict__ cj,
    unsigned char* __restrict__ Li8, unsigned char* __restrict__ Qb8,
    float* __restrict__ hneg, float* __restrict__ isc,
    float* __restrict__ rowsum, float* __restrict__ out)
{
  const int lane = threadIdx.x & 63;
  const int wave = threadIdx.x >> 6;
  const int row = blockIdx.x * 4 + wave;
  const bool isj = row >= BATCH;
  const int r = isj ? row - BATCH : row;
  const float* __restrict__ src = (isj ? cj : ci) + (size_t)r * DIM;

  // 32 elements per lane: float4 chunks at [i*64 + lane], i = 0..7
  float v[32];
  #pragma unroll
  for (int i = 0; i < 8; ++i) {
    float4 t = ((const float4*)src)[i * 64 + lane];
    v[i * 4 + 0] = t.x; v[i * 4 + 1] = t.y;
    v[i * 4 + 2] = t.z; v[i * 4 + 3] = t.w;
  }

  // wave max
  float m = v[0];
  #pragma unroll
  for (int i = 1; i < 32; ++i) m = fmaxf(m, v[i]);
  #pragma unroll
  for (int off = 32; off >= 1; off >>= 1) m = fmaxf(m, __shfl_xor(m, off));

  // wave sum of exp(v - m); keep e for the Q pass
  float e[32];
  float s = 0.f;
  #pragma unroll
  for (int i = 0; i < 32; ++i) { e[i] = __expf(v[i] - m); s += e[i]; }
  #pragma unroll
  for (int off = 32; off >= 1; off >>= 1) s += __shfl_xor(s, off);
  const float ls = m + __logf(s);          // logsumexp of row
  const float inv_s = 1.0f / s;

  // per-row pow2 scale for Q rows: Qmax = exp(m - ls); want Qmax*2^t in [128,256)
  float scale = 1.f;
  int t = 0;
  if (isj) {
    const float qmax = inv_s;              // exp(m - ls) = 1/s
    const int be = (int)((__float_as_uint(qmax) >> 23) & 0xff);
    t = 134 - be;                          // qmax*2^t in [128,256)
    scale = __uint_as_float((unsigned)(t + 127) << 23);
  }

  unsigned char* dst = (isj ? Qb8 : Li8) + (size_t)r * DIM;
  float h = 0.f;
  #pragma unroll
  for (int i = 0; i < 8; ++i) {
    float f[4];
    #pragma unroll
    for (int j = 0; j < 4; ++j) {
      const float li = v[i * 4 + j] - ls;  // log_softmax element
      if (isj) {
        const float q = e[i * 4 + j] * inv_s;  // exact softmax element
        h += q * li;                       // negative entropy (fp32, exact Q)
        f[j] = q * scale;
      } else {
        f[j] = li;
      }
    }
    int w = __builtin_amdgcn_cvt_pk_fp8_f32(f[0], f[1], 0, false);
    w = __builtin_amdgcn_cvt_pk_fp8_f32(f[2], f[3], w, true);
    ((int*)dst)[i * 64 + lane] = w;        // bytes (i*256 + lane*4) ..+3
  }

  if (isj) {
    #pragma unroll
    for (int off = 32; off >= 1; off >>= 1) h += __shfl_xor(h, off);
    if (lane == 0) {
      hneg[r] = h;
      isc[r] = __uint_as_float((unsigned)(127 - t) << 23);  // 2^-t
      rowsum[r] = 0.f;
    }
  }
  if (row == 0 && lane == 0) out[0] = 0.f;
}

// ---------------------------------------------------------------------------
// Kernel 2 (R13): cross' = Li8 @ Qb8^T via MX-fp8 MFMA (16x16x128).
// R8/R9/R12 all pinned at ~8000 cy/K-tile (MfmaUtil 23%) with 2 waves/SIMD:
// ~250 regs/wave (128 acc-AGPR + ~124 VGPR) caps the unified 512-reg/SIMD
// file at 2 waves -> contended LDS/L2 latency between ds_read and MFMA is
// unhideable; intra-wave reordering (R9/R10/R12) can't fix occupancy.
// R13: 16 waves x 64x64 wave tiles (1024-thread block). acc 128 -> 64
// regs/wave; total ~120 < 128 -> 4 waves/SIMD (2x TLP). B back in LDS
// (row-major staging, R8/R9-verified read path; 64x64 split would double
// B L2 traffic under the R12 bypass and L2 fabric ~8.9 TB/s is real).
// No af ping-pong: TLP replaces ILP, saves the knife-edge registers.
// Per CU/tile: LDS ~2550 cy, MFMA 2211 cy, counted vmcnt(4) + 2 barriers.
// ---------------------------------------------------------------------------
__global__ __launch_bounds__(1024, 1) void gemm_lse_kernel(
    const unsigned char* __restrict__ Li8, const unsigned char* __restrict__ Qb8,
    const float* __restrict__ hneg, const float* __restrict__ isc,
    float* __restrict__ rowsum, float* __restrict__ diag)
{
  // 2 dbuf x (A 256x128 + B 256x128) fp8 = 128 KB
  __shared__ __attribute__((aligned(16))) unsigned char As_[2][BM * 128];
  __shared__ __attribute__((aligned(16))) unsigned char Bs_[2][BN * 128];

  const int tid  = threadIdx.x;
  // XCD-aware patch mapping: 256 blocks, xcd = lin&7 owns a 4(by) x 8(bx)
  // rectangle of the 16x16 tile grid (bijective).
  const int lin = blockIdx.x;
  const int xc  = lin & 7;
  const int sq  = lin >> 3;                // 0..31
  const int by  = (xc & 3) * 4 + (sq & 3);
  const int bx  = (xc >> 2) * 8 + (sq >> 2);

  const int lane = tid & 63;
  const int wave = tid >> 6;               // 0..15
  const int ww   = wave >> 2;              // 0..3 -> row band ww*64
  const int wc   = wave & 3;               // 0..3 -> col band wc*64

  // staging: 2048 16B-chunks per operand-tile; thread t does chunks t+1024*s.
  // LDS chunk p holds global chunk (row = p>>3, cb = (p&7) ^ (row&7)).
  int soff[2];
  #pragma unroll
  for (int s = 0; s < 2; ++s) {
    const int p = tid + 1024 * s;
    const int row = p >> 3;
    const int cbg = (p & 7) ^ (row & 7);
    soff[s] = row * DIM + cbg * 16;
  }
  const unsigned char* Abase = Li8 + (size_t)(by * BM) * DIM;
  const unsigned char* Bbase = Qb8 + (size_t)(bx * BN) * DIM;

  const int rl = lane & 15;                // m/n within frag; col within C/D
  const int q  = lane >> 4;                // k-quad: k in [q*32, q*32+32)
  const int sw = rl & 7;                   // XOR swizzle key (row & 7)

  floatx4 acc[4][4];                       // 64 regs: wave tile 64x64
  const floatx4 z = {0.f, 0.f, 0.f, 0.f};
  #pragma unroll
  for (int mt = 0; mt < 4; ++mt)
    #pragma unroll
    for (int nt = 0; nt < 4; ++nt) acc[mt][nt] = z;

  // prologue: stage K-tile 0 into buffer 0 (4 loads/thread)
  #pragma unroll
  for (int s = 0; s < 2; ++s) {
    gld_lds16(Abase + soff[s], &As_[0][0] + (tid + 1024 * s) * 16);
    gld_lds16(Bbase + soff[s], &Bs_[0][0] + (tid + 1024 * s) * 16);
  }

  for (int t = 0; t < 16; ++t) {
    const int cur = t & 1;
    const unsigned char* Ab = &As_[cur][0];
    const unsigned char* Bb = &Bs_[cur][0];

    // issue next tile's 4 staging loads, then counted wait: vmcnt(4) = tile
    // t's loads have landed, t+1's 4 stay in flight across the barrier (T4).
    if (t < 15) {
      unsigned char* An = &As_[cur ^ 1][0];
      unsigned char* Bn = &Bs_[cur ^ 1][0];
      const int kn = (t + 1) * 128;
      #pragma unroll
      for (int s = 0; s < 2; ++s) {
        gld_lds16(Abase + soff[s] + kn, An + (tid + 1024 * s) * 16);
        gld_lds16(Bbase + soff[s] + kn, Bn + (tid + 1024 * s) * 16);
      }
      asm volatile("s_waitcnt vmcnt(4)" ::: "memory");
    } else {
      asm volatile("s_waitcnt vmcnt(0)" ::: "memory");
    }
    asm volatile("s_barrier" ::: "memory");

    // B fragments for the whole K-tile (32 VGPRs)
    intx8 bf[4];
    #pragma unroll
    for (int nt = 0; nt < 4; ++nt) {
      const int rb = wc * 64 + nt * 16 + rl;
      const int q0 = rb * 8 + ((2 * q) ^ sw);
      const int q1 = rb * 8 + ((2 * q + 1) ^ sw);
      bf[nt] = comb8(*(const intx4*)(Bb + q0 * 16),
                     *(const intx4*)(Bb + q1 * 16));
    }
    // A fragments streamed per 4-MFMA burst (8 regs live; 4 waves/SIMD
    // provide the latency hiding that ping-pong ILP used to attempt).
    #pragma unroll
    for (int mt = 0; mt < 4; ++mt) {
      const int ra = ww * 64 + mt * 16 + rl;
      const int a0 = ra * 8 + ((2 * q) ^ sw);
      const int a1 = ra * 8 + ((2 * q + 1) ^ sw);
      const intx8 af = comb8(*(const intx4*)(Ab + a0 * 16),
                             *(const intx4*)(Ab + a1 * 16));
      __builtin_amdgcn_s_setprio(1);
      #pragma unroll
      for (int nt = 0; nt < 4; ++nt)
        acc[mt][nt] = __builtin_amdgcn_mfma_scale_f32_16x16x128_f8f6f4(
            af, bf[nt], acc[mt][nt],
            0, 0,            // cbsz = fp8(e4m3), blgp = fp8(e4m3)
            0, 127,          // scale A: 1.0
            0, 127);         // scale B: 1.0
      __builtin_amdgcn_s_setprio(0);
    }

    // end barrier: all waves done reading buf[cur] before t+1 stages into it
    asm volatile("s_barrier" ::: "memory");
  }

  // ---- epilogue. C/D layout: col = lane&15, row = (lane>>4)*4 + reg ----
  const int col0 = bx * BN + wc * 64 + rl;
  float hn[4], sc[4];
  #pragma unroll
  for (int nt = 0; nt < 4; ++nt) {
    hn[nt] = hneg[col0 + nt * 16];
    sc[nt] = isc[col0 + nt * 16];
  }
  const int row0 = by * BM + ww * 64 + (q << 2);

  // diag: wave covers rows [ww*64,+64) x cols [wc*64,+64); diagonal hits
  // iff bx==by && ww==wc; then local row==col => mt==nt, q==rl>>2, rr==rl&3.
  // acc indices compile-time (rule #20); runtime tests in the predicate.
  if (bx == by && ww == wc && q == (rl >> 2)) {
    #pragma unroll
    for (int nt = 0; nt < 4; ++nt) {
      #pragma unroll
      for (int rr = 0; rr < 4; ++rr) {
        if ((rl & 3) == rr)
          diag[bx * BN + wc * 64 + nt * 16 + rl] = acc[nt][nt][rr] * sc[nt];
      }
    }
  }

  #pragma unroll
  for (int mt = 0; mt < 4; ++mt) {
    #pragma unroll
    for (int rr = 0; rr < 4; ++rr) {
      float p = 0.f;
      #pragma unroll
      for (int nt = 0; nt < 4; ++nt)
        p += __expf(INV_T * (acc[mt][nt][rr] * sc[nt] - hn[nt]));
      // reduce across 16 cols (lane&15 group)
      p += __shfl_xor(p, 1);
      p += __shfl_xor(p, 2);
      p += __shfl_xor(p, 4);
      p += __shfl_xor(p, 8);
      if (rl == 0)
        atomicAdd(&rowsum[row0 + mt * 16 + rr], p);
    }
  }
}

// ---------------------------------------------------------------------------
// Kernel 3: loss = (1/B) sum_i [ log(rowsum[i]) - INV_T*(diag[i] - hneg[i]) ]
// ---------------------------------------------------------------------------
__global__ __launch_bounds__(256) void finalize_kernel(
    const float* __restrict__ hneg, const float* __restrict__ rowsum,
    const float* __restrict__ diag, float* __restrict__ out)
{
  const int i = blockIdx.x * 256 + threadIdx.x;
  const int lane = threadIdx.x & 63;
  const int wave = threadIdx.x >> 6;

  float c = __logf(rowsum[i]) - INV_T * (diag[i] - hneg[i]);
  #pragma unroll
  for (int off = 32; off >= 1; off >>= 1) c += __shfl_xor(c, off);

  __shared__ float red[4];
  if (lane == 0) red[wave] = c;
  __syncthreads();
  if (threadIdx.x == 0)
    atomicAdd(out, (red[0] + red[1] + red[2] + red[3]) * (1.0f / BATCH));
}

// ---------------------------------------------------------------------------
extern "C" void kernel_launch(void* const* d_in, const int* in_sizes, int n_in,
                              void* d_out, int out_size, void* d_ws, size_t ws_size,
                              hipStream_t stream) {
  const float* ci = (const float*)d_in[0];
  const float* cj = (const float*)d_in[1];
  float* out = (float*)d_out;

  // ws: Li8 u8[B*D] | Qb8 u8[B*D] | hneg f32[B] | isc f32[B] | rowsum f32[B] | diag f32[B]
  unsigned char* Li8 = (unsigned char*)d_ws;
  unsigned char* Qb8 = Li8 + (size_t)BATCH * DIM;
  float* hneg   = (float*)(Qb8 + (size_t)BATCH * DIM);
  float* isc    = hneg + BATCH;
  float* rowsum = isc + BATCH;
  float* diag   = rowsum + BATCH;

  prep_kernel<<<2 * BATCH / 4, 256, 0, stream>>>(ci, cj, Li8, Qb8, hneg, isc, rowsum, out);
  gemm_lse_kernel<<<(BATCH / BM) * (BATCH / BN), 1024, 0, stream>>>(Li8, Qb8, hneg, isc, rowsum, diag);
  finalize_kernel<<<BATCH / 256, 256, 0, stream>>>(hneg, rowsum, diag, out);
}

// Round 10
// 161.487 us; speedup vs baseline: 1.4397x; 1.4397x over previous
//
#include <hip/hip_runtime.h>
#include <hip/hip_bf16.h>
#include <math.h>

#define BATCH 4096
#define DIM   2048
#define INV_T 2.0f   // 1 / TEMPERATURE, TEMPERATURE = 0.5

#define BM 256
#define BN 256

typedef float floatx4 __attribute__((ext_vector_type(4)));
typedef int   intx4   __attribute__((ext_vector_type(4)));
typedef int   intx8   __attribute__((ext_vector_type(8)));

static __device__ __forceinline__ void gld_lds16(const void* g, void* l) {
  __builtin_amdgcn_global_load_lds(
      (const __attribute__((address_space(1))) void*)g,
      (__attribute__((address_space(3))) void*)l, 16, 0, 0);
}

static __device__ __forceinline__ intx8 comb8(intx4 lo, intx4 hi) {
  intx8 r;
  r[0] = lo[0]; r[1] = lo[1]; r[2] = lo[2]; r[3] = lo[3];
  r[4] = hi[0]; r[5] = hi[1]; r[6] = hi[2]; r[7] = hi[3];
  return r;
}

// ---------------------------------------------------------------------------
// Kernel 1: per-row log-softmax prep. Wave-per-row, NO barriers.
// R12-verified structure: Li8 row-major; Qb8 FRAGMENT-MAJOR
//   (byte offset = jb*32768 + kt*2048 + lane'*32 + (k&31), jb=j>>4, kt=k>>7,
//    lane' = ((k>>5)&3)*16 + (j&15)) so gemm loads B global->reg coalesced.
// R13's verified arithmetic merged: single exp pass (reuse e = exp(v-m)).
// ---------------------------------------------------------------------------
__global__ __launch_bounds__(256) void prep_kernel(
    const float* __restrict__ ci, const float* __restrict__ cj,
    unsigned char* __restrict__ Li8, unsigned char* __restrict__ Qb8,
    float* __restrict__ hneg, float* __restrict__ isc,
    float* __restrict__ rowsum, float* __restrict__ out)
{
  const int lane = threadIdx.x & 63;
  const int wave = threadIdx.x >> 6;
  const int row = blockIdx.x * 4 + wave;
  const bool isj = row >= BATCH;
  const int r = isj ? row - BATCH : row;
  const float* __restrict__ src = (isj ? cj : ci) + (size_t)r * DIM;

  // 32 elements per lane: float4 chunks at [i*64 + lane], i = 0..7
  float v[32];
  #pragma unroll
  for (int i = 0; i < 8; ++i) {
    float4 t = ((const float4*)src)[i * 64 + lane];
    v[i * 4 + 0] = t.x; v[i * 4 + 1] = t.y;
    v[i * 4 + 2] = t.z; v[i * 4 + 3] = t.w;
  }

  // wave max
  float m = v[0];
  #pragma unroll
  for (int i = 1; i < 32; ++i) m = fmaxf(m, v[i]);
  #pragma unroll
  for (int off = 32; off >= 1; off >>= 1) m = fmaxf(m, __shfl_xor(m, off));

  // wave sum of exp(v - m); keep e for the Q pass
  float e[32];
  float s = 0.f;
  #pragma unroll
  for (int i = 0; i < 32; ++i) { e[i] = __expf(v[i] - m); s += e[i]; }
  #pragma unroll
  for (int off = 32; off >= 1; off >>= 1) s += __shfl_xor(s, off);
  const float ls = m + __logf(s);          // logsumexp of row
  const float inv_s = 1.0f / s;

  // per-row pow2 scale for Q rows: Qmax = exp(m-ls) = 1/s; Qmax*2^t in [128,256)
  float scale = 1.f;
  int t = 0;
  if (isj) {
    const int be = (int)((__float_as_uint(inv_s) >> 23) & 0xff);
    t = 134 - be;
    scale = __uint_as_float((unsigned)(t + 127) << 23);
  }

  unsigned char* dst = Li8 + (size_t)r * DIM;
  float h = 0.f;
  #pragma unroll
  for (int i = 0; i < 8; ++i) {
    float f[4];
    #pragma unroll
    for (int j = 0; j < 4; ++j) {
      const float li = v[i * 4 + j] - ls;  // log_softmax element
      if (isj) {
        const float q = e[i * 4 + j] * inv_s;  // exact softmax element
        h += q * li;                       // negative entropy (fp32, exact Q)
        f[j] = q * scale;
      } else {
        f[j] = li;
      }
    }
    int w = __builtin_amdgcn_cvt_pk_fp8_f32(f[0], f[1], 0, false);
    w = __builtin_amdgcn_cvt_pk_fp8_f32(f[2], f[3], w, true);
    if (isj) {
      // fragment-major (R11/R12-verified): this int covers k=i*256+lane*4..+3
      // int index bits: [jb:13+][kt:9..12][kq:7..8][jr:3..6][word:0..2]
      const int idx = ((r >> 4) << 13) | ((i * 2 + (lane >> 5)) << 9)
                    | (((lane >> 3) & 3) << 7) | ((r & 15) << 3) | (lane & 7);
      ((int*)Qb8)[idx] = w;
    } else {
      ((int*)dst)[i * 64 + lane] = w;      // row-major
    }
  }

  if (isj) {
    #pragma unroll
    for (int off = 32; off >= 1; off >>= 1) h += __shfl_xor(h, off);
    if (lane == 0) {
      hneg[r] = h;
      isc[r] = __uint_as_float((unsigned)(127 - t) << 23);  // 2^-t
      rowsum[r] = 0.f;
    }
  }
  if (row == 0 && lane == 0) out[0] = 0.f;
}

// ---------------------------------------------------------------------------
// Kernel 2 (R14): cross' = Li8 @ Qb8^T via MX-fp8 MFMA (16x16x128).
// Register law (R10/R11/R13 spills): VGPR+AGPR <= 256/wave at 2 waves/SIMD;
// acc=128 AGPR => hard 128-VGPR cap. R12 (124 VGPR, no spill) is the base.
// R14 de-convoys R12 with zero extra registers:
//  (a) 3-stage A-LDS rotation (32 KB x 3 = 96 KB): compute buf[t%3], stage
//      into buf[(t+2)%3] -> ONE barrier/tile (was 2), one-tile slack.
//  (b) bf(t+1) issued in the SAME 32 regs right after tile t's last MFMA
//      burst (T14 async-split): ~800+ cy of cover vs ~100 before.
// Counted vmcnt(4)/tile: leaves stage(t+2) in flight; forces bf(t) + all
// older staging retired. B stays fragment-major global->reg (R12 path).
// ---------------------------------------------------------------------------
__global__ __launch_bounds__(512, 1) void gemm_lse_kernel(
    const unsigned char* __restrict__ Li8, const unsigned char* __restrict__ Qb8,
    const float* __restrict__ hneg, const float* __restrict__ isc,
    float* __restrict__ rowsum, float* __restrict__ diag)
{
  // 3-stage A rotation: 3 x 256x128 fp8 = 96 KB. B is register-resident.
  __shared__ __attribute__((aligned(16))) unsigned char As_[3][BM * 128];

  const int tid  = threadIdx.x;
  // XCD-aware patch mapping: 256 blocks, xcd = lin&7 owns a 4(by) x 8(bx)
  // rectangle of the 16x16 tile grid (bijective).
  const int lin = blockIdx.x;
  const int xc  = lin & 7;
  const int sq  = lin >> 3;                // 0..31
  const int by  = (xc & 3) * 4 + (sq & 3);
  const int bx  = (xc >> 2) * 8 + (sq >> 2);

  const int lane = tid & 63;
  const int wave = tid >> 6;               // 0..7
  const int wm   = wave >> 2;              // 0..1 -> row band wm*128
  const int wn   = wave & 3;               // 0..3 -> col band wn*64

  // A staging: 2048 16B-chunks per tile; thread t does chunks t+512*s.
  // LDS chunk p holds global chunk (row = p>>3, cb = (p&7) ^ (row&7)).
  int soff[4];
  #pragma unroll
  for (int s = 0; s < 4; ++s) {
    const int p = tid + 512 * s;
    const int row = p >> 3;
    const int cbg = (p & 7) ^ (row & 7);
    soff[s] = row * DIM + cbg * 16;
  }
  const unsigned char* Abase = Li8 + (size_t)(by * BM) * DIM;
  // B fragment-major base for this wave: j-block jb0 = bx*16 + wn*4; lane's
  // 32B chunk at +lane*32. Per (nt, tile): + nt*32768 + t*2048.
  const unsigned char* Bfbase =
      Qb8 + (size_t)(bx * 16 + wn * 4) * 32768 + lane * 32;

  const int rl = lane & 15;                // m/n within frag; col within C/D
  const int q  = lane >> 4;                // k-quad: k in [q*32, q*32+32)
  const int sw = rl & 7;                   // XOR swizzle key (row & 7)

  floatx4 acc[8][4];
  const floatx4 z = {0.f, 0.f, 0.f, 0.f};
  #pragma unroll
  for (int mt = 0; mt < 8; ++mt)
    #pragma unroll
    for (int nt = 0; nt < 4; ++nt) acc[mt][nt] = z;

  // prologue: stage tiles 0,1 into buf0,buf1; load bf(0) into regs.
  #pragma unroll
  for (int s = 0; s < 4; ++s)
    gld_lds16(Abase + soff[s], &As_[0][0] + (tid + 512 * s) * 16);
  #pragma unroll
  for (int s = 0; s < 4; ++s)
    gld_lds16(Abase + soff[s] + 128, &As_[1][0] + (tid + 512 * s) * 16);
  intx8 bf[4];
  #pragma unroll
  for (int nt = 0; nt < 4; ++nt)
    bf[nt] = comb8(*(const intx4*)(Bfbase + nt * 32768),
                   *(const intx4*)(Bfbase + nt * 32768 + 16));

  // Per tile T: barrier -> stage(T+2) -> vmcnt -> af/MFMA on CURBUF ->
  // issue bf(T+1) into the same regs after the last MFMA burst.
#define KTILE(T, CURBUF, STGBUF)                                              \
  {                                                                           \
    const int t_ = (T);                                                       \
    asm volatile("s_barrier" ::: "memory");                                   \
    if (t_ <= 13) {                                                           \
      const int kn = (t_ + 2) * 128;                                          \
      _Pragma("unroll")                                                       \
      for (int s = 0; s < 4; ++s)                                             \
        gld_lds16(Abase + soff[s] + kn,                                       \
                  &As_[STGBUF][0] + (tid + 512 * s) * 16);                    \
      asm volatile("s_waitcnt vmcnt(4)" ::: "memory");                        \
    } else {                                                                  \
      asm volatile("s_waitcnt vmcnt(0)" ::: "memory");                        \
    }                                                                         \
    const unsigned char* Ab = &As_[CURBUF][0];                                \
    intx8 af[2];                                                              \
    {                                                                         \
      const int ra = wm * 128 + rl;                                           \
      const int a0 = ra * 8 + ((2 * q) ^ sw);                                 \
      const int a1 = ra * 8 + ((2 * q + 1) ^ sw);                             \
      af[0] = comb8(*(const intx4*)(Ab + a0 * 16),                            \
                    *(const intx4*)(Ab + a1 * 16));                           \
    }                                                                         \
    _Pragma("unroll")                                                         \
    for (int s = 0; s < 8; ++s) {                                             \
      if (s < 7) {                                                            \
        const int ra = wm * 128 + (s + 1) * 16 + rl;                          \
        const int a0 = ra * 8 + ((2 * q) ^ sw);                               \
        const int a1 = ra * 8 + ((2 * q + 1) ^ sw);                           \
        af[(s + 1) & 1] = comb8(*(const intx4*)(Ab + a0 * 16),                \
                                *(const intx4*)(Ab + a1 * 16));               \
      }                                                                       \
      __builtin_amdgcn_s_setprio(1);                                          \
      _Pragma("unroll")                                                       \
      for (int nt = 0; nt < 4; ++nt)                                          \
        acc[s][nt] = __builtin_amdgcn_mfma_scale_f32_16x16x128_f8f6f4(        \
            af[s & 1], bf[nt], acc[s][nt],                                    \
            0, 0,   /* cbsz = fp8(e4m3), blgp = fp8(e4m3) */                  \
            0, 127, /* scale A: 1.0 */                                        \
            0, 127);/* scale B: 1.0 */                                        \
      __builtin_amdgcn_s_setprio(0);                                          \
    }                                                                         \
    if (t_ <= 14) {                                                           \
      /* bf(t+1) into the same regs: WAR after last use, ~1 tile of cover */  \
      const unsigned char* Bt = Bfbase + (t_ + 1) * 2048;                     \
      _Pragma("unroll")                                                       \
      for (int nt = 0; nt < 4; ++nt)                                          \
        bf[nt] = comb8(*(const intx4*)(Bt + nt * 32768),                      \
                       *(const intx4*)(Bt + nt * 32768 + 16));                \
    }                                                                         \
  }

  for (int tt = 0; tt < 5; ++tt) {
    KTILE(3 * tt + 0, 0, 2);
    KTILE(3 * tt + 1, 1, 0);
    KTILE(3 * tt + 2, 2, 1);
  }
  KTILE(15, 0, 2);
#undef KTILE

  // ---- epilogue. C/D layout: col = lane&15, row = (lane>>4)*4 + reg ----
  const int col0 = bx * BN + wn * 64 + rl;
  float hn[4], sc[4];
  #pragma unroll
  for (int nt = 0; nt < 4; ++nt) {
    hn[nt] = hneg[col0 + nt * 16];
    sc[nt] = isc[col0 + nt * 16];
  }
  const int row0 = by * BM + wm * 128 + (q << 2);

  // diag: rows wm*128.. overlap cols wn*64.. iff wm == wn>>1; row==col picks
  // mt = (wn&1)*4 + nt, q == rl>>2, reg rr == rl&3. ALL acc indices below are
  // compile-time (rule #20); runtime selection lives in the store predicate.
  if (bx == by && wm == (wn >> 1) && q == (rl >> 2)) {
    #pragma unroll
    for (int half = 0; half < 2; ++half) {
      #pragma unroll
      for (int nt = 0; nt < 4; ++nt) {
        #pragma unroll
        for (int rr = 0; rr < 4; ++rr) {
          if ((wn & 1) == half && (rl & 3) == rr)
            diag[bx * BN + wn * 64 + nt * 16 + rl] =
                acc[half * 4 + nt][nt][rr] * sc[nt];
        }
      }
    }
  }

  #pragma unroll
  for (int mt = 0; mt < 8; ++mt) {
    #pragma unroll
    for (int rr = 0; rr < 4; ++rr) {
      float p = 0.f;
      #pragma unroll
      for (int nt = 0; nt < 4; ++nt)
        p += __expf(INV_T * (acc[mt][nt][rr] * sc[nt] - hn[nt]));
      // reduce across 16 cols (lane&15 group)
      p += __shfl_xor(p, 1);
      p += __shfl_xor(p, 2);
      p += __shfl_xor(p, 4);
      p += __shfl_xor(p, 8);
      if (rl == 0)
        atomicAdd(&rowsum[row0 + mt * 16 + rr], p);
    }
  }
}

// ---------------------------------------------------------------------------
// Kernel 3: loss = (1/B) sum_i [ log(rowsum[i]) - INV_T*(diag[i] - hneg[i]) ]
// ---------------------------------------------------------------------------
__global__ __launch_bounds__(256) void finalize_kernel(
    const float* __restrict__ hneg, const float* __restrict__ rowsum,
    const float* __restrict__ diag, float* __restrict__ out)
{
  const int i = blockIdx.x * 256 + threadIdx.x;
  const int lane = threadIdx.x & 63;
  const int wave = threadIdx.x >> 6;

  float c = __logf(rowsum[i]) - INV_T * (diag[i] - hneg[i]);
  #pragma unroll
  for (int off = 32; off >= 1; off >>= 1) c += __shfl_xor(c, off);

  __shared__ float red[4];
  if (lane == 0) red[wave] = c;
  __syncthreads();
  if (threadIdx.x == 0)
    atomicAdd(out, (red[0] + red[1] + red[2] + red[3]) * (1.0f / BATCH));
}

// ---------------------------------------------------------------------------
extern "C" void kernel_launch(void* const* d_in, const int* in_sizes, int n_in,
                              void* d_out, int out_size, void* d_ws, size_t ws_size,
                              hipStream_t stream) {
  const float* ci = (const float*)d_in[0];
  const float* cj = (const float*)d_in[1];
  float* out = (float*)d_out;

  // ws: Li8 u8[B*D] | Qb8 u8[B*D] | hneg f32[B] | isc f32[B] | rowsum f32[B] | diag f32[B]
  unsigned char* Li8 = (unsigned char*)d_ws;
  unsigned char* Qb8 = Li8 + (size_t)BATCH * DIM;
  float* hneg   = (float*)(Qb8 + (size_t)BATCH * DIM);
  float* isc    = hneg + BATCH;
  float* rowsum = isc + BATCH;
  float* diag   = rowsum + BATCH;

  prep_kernel<<<2 * BATCH / 4, 256, 0, stream>>>(ci, cj, Li8, Qb8, hneg, isc, rowsum, out);
  gemm_lse_kernel<<<(BATCH / BM) * (BATCH / BN), 512, 0, stream>>>(Li8, Qb8, hneg, isc, rowsum, diag);
  finalize_kernel<<<BATCH / 256, 256, 0, stream>>>(hneg, rowsum, diag, out);
}

// Round 11
// 143.270 us; speedup vs baseline: 1.6228x; 1.1272x over previous
//
#include <hip/hip_runtime.h>
#include <hip/hip_bf16.h>
#include <math.h>

#define BATCH 4096
#define DIM   2048
#define INV_T 2.0f   // 1 / TEMPERATURE, TEMPERATURE = 0.5

#define BM 256
#define BN 256

typedef float floatx4 __attribute__((ext_vector_type(4)));
typedef int   intx4   __attribute__((ext_vector_type(4)));
typedef int   intx8   __attribute__((ext_vector_type(8)));

static __device__ __forceinline__ void gld_lds16(const void* g, void* l) {
  __builtin_amdgcn_global_load_lds(
      (const __attribute__((address_space(1))) void*)g,
      (__attribute__((address_space(3))) void*)l, 16, 0, 0);
}

static __device__ __forceinline__ intx8 comb8(intx4 lo, intx4 hi) {
  intx8 r;
  r[0] = lo[0]; r[1] = lo[1]; r[2] = lo[2]; r[3] = lo[3];
  r[4] = hi[0]; r[5] = hi[1]; r[6] = hi[2]; r[7] = hi[3];
  return r;
}

// ---------------------------------------------------------------------------
// Kernel 1: per-row log-softmax prep. Wave-per-row, NO barriers. Row-major
// outputs (R9 gemm path). Single exp pass (R13/R14-verified): reuse
// e = exp(v-m) from the sum pass for the Q pass. Also zeroes rowsum and the
// gemm completion counter (graph-replay safe: runs every iteration).
// ---------------------------------------------------------------------------
__global__ __launch_bounds__(256) void prep_kernel(
    const float* __restrict__ ci, const float* __restrict__ cj,
    unsigned char* __restrict__ Li8, unsigned char* __restrict__ Qb8,
    float* __restrict__ hneg, float* __restrict__ isc,
    float* __restrict__ rowsum, unsigned* __restrict__ cnt)
{
  const int lane = threadIdx.x & 63;
  const int wave = threadIdx.x >> 6;
  const int row = blockIdx.x * 4 + wave;
  const bool isj = row >= BATCH;
  const int r = isj ? row - BATCH : row;
  const float* __restrict__ src = (isj ? cj : ci) + (size_t)r * DIM;

  // 32 elements per lane: float4 chunks at [i*64 + lane], i = 0..7
  float v[32];
  #pragma unroll
  for (int i = 0; i < 8; ++i) {
    float4 t = ((const float4*)src)[i * 64 + lane];
    v[i * 4 + 0] = t.x; v[i * 4 + 1] = t.y;
    v[i * 4 + 2] = t.z; v[i * 4 + 3] = t.w;
  }

  // wave max
  float m = v[0];
  #pragma unroll
  for (int i = 1; i < 32; ++i) m = fmaxf(m, v[i]);
  #pragma unroll
  for (int off = 32; off >= 1; off >>= 1) m = fmaxf(m, __shfl_xor(m, off));

  // wave sum of exp(v - m); keep e for the Q pass (single exp pass)
  float e[32];
  float s = 0.f;
  #pragma unroll
  for (int i = 0; i < 32; ++i) { e[i] = __expf(v[i] - m); s += e[i]; }
  #pragma unroll
  for (int off = 32; off >= 1; off >>= 1) s += __shfl_xor(s, off);
  const float ls = m + __logf(s);          // logsumexp of row
  const float inv_s = 1.0f / s;

  // per-row pow2 scale for Q rows: Qmax = exp(m-ls) = 1/s; Qmax*2^t in [128,256)
  float scale = 1.f;
  int t = 0;
  if (isj) {
    const int be = (int)((__float_as_uint(inv_s) >> 23) & 0xff);
    t = 134 - be;
    scale = __uint_as_float((unsigned)(t + 127) << 23);
  }

  unsigned char* dst = (isj ? Qb8 : Li8) + (size_t)r * DIM;
  float h = 0.f;
  #pragma unroll
  for (int i = 0; i < 8; ++i) {
    float f[4];
    #pragma unroll
    for (int j = 0; j < 4; ++j) {
      const float li = v[i * 4 + j] - ls;  // log_softmax element
      if (isj) {
        const float q = e[i * 4 + j] * inv_s;  // exact softmax element
        h += q * li;                       // negative entropy (fp32, exact Q)
        f[j] = q * scale;
      } else {
        f[j] = li;
      }
    }
    int w = __builtin_amdgcn_cvt_pk_fp8_f32(f[0], f[1], 0, false);
    w = __builtin_amdgcn_cvt_pk_fp8_f32(f[2], f[3], w, true);
    ((int*)dst)[i * 64 + lane] = w;        // bytes (i*256 + lane*4) ..+3
  }

  if (isj) {
    #pragma unroll
    for (int off = 32; off >= 1; off >>= 1) h += __shfl_xor(h, off);
    if (lane == 0) {
      hneg[r] = h;
      isc[r] = __uint_as_float((unsigned)(127 - t) << 23);  // 2^-t
      rowsum[r] = 0.f;
    }
  }
  if (row == 0 && lane == 0) cnt[0] = 0u;  // gemm last-block counter
}

// ---------------------------------------------------------------------------
// Kernel 2 (R15): cross' = Li8 @ Qb8^T via MX-fp8 MFMA (16x16x128).
// Main loop = R9 VERBATIM (best measured: 53.1 us, no spill, VGPR 128):
// 256^2 tile, 8 waves, A+B LDS dbuf, 2 barriers/tile, counted vmcnt(8),
// af ping-pong, setprio per 4-MFMA burst. R15 adds a fused finalize:
// diag via atomicExch (device-scope, XCD-safe), then syncthreads ->
// threadfence -> counter atomicAdd; the 256th block computes the loss
// (removes the finalize launch). Deadlock-free: no block ever waits.
// ---------------------------------------------------------------------------
__global__ __launch_bounds__(512, 1) void gemm_lse_kernel(
    const unsigned char* __restrict__ Li8, const unsigned char* __restrict__ Qb8,
    const float* __restrict__ hneg, const float* __restrict__ isc,
    float* __restrict__ rowsum, float* __restrict__ diag,
    unsigned* __restrict__ cnt, float* __restrict__ out)
{
  // 2 dbuf x (A 256x128 + B 256x128) fp8 = 128 KB
  __shared__ __attribute__((aligned(16))) unsigned char As_[2][BM * 128];
  __shared__ __attribute__((aligned(16))) unsigned char Bs_[2][BN * 128];

  const int tid  = threadIdx.x;
  // XCD-aware patch mapping: 256 blocks, xcd = lin&7 owns a 4(by) x 8(bx)
  // rectangle of the 16x16 tile grid (bijective).
  const int lin = blockIdx.x;
  const int xc  = lin & 7;
  const int sq  = lin >> 3;                // 0..31
  const int by  = (xc & 3) * 4 + (sq & 3);
  const int bx  = (xc >> 2) * 8 + (sq >> 2);

  const int lane = tid & 63;
  const int wave = tid >> 6;               // 0..7
  const int wm   = wave >> 2;              // 0..1 -> row band wm*128
  const int wn   = wave & 3;               // 0..3 -> col band wn*64

  // staging: 2048 16B-chunks per operand-tile; thread t does chunks t+512*s.
  // LDS chunk p holds global chunk (row = p>>3, cb = (p&7) ^ (row&7)).
  int soff[4];
  #pragma unroll
  for (int s = 0; s < 4; ++s) {
    const int p = tid + 512 * s;
    const int row = p >> 3;
    const int cbg = (p & 7) ^ (row & 7);
    soff[s] = row * DIM + cbg * 16;
  }
  const unsigned char* Abase = Li8 + (size_t)(by * BM) * DIM;
  const unsigned char* Bbase = Qb8 + (size_t)(bx * BN) * DIM;

  const int rl = lane & 15;                // m/n within frag; col within C/D
  const int q  = lane >> 4;                // k-quad: k in [q*32, q*32+32)
  const int sw = rl & 7;                   // XOR swizzle key (row & 7)

  floatx4 acc[8][4];
  const floatx4 z = {0.f, 0.f, 0.f, 0.f};
  #pragma unroll
  for (int mt = 0; mt < 8; ++mt)
    #pragma unroll
    for (int nt = 0; nt < 4; ++nt) acc[mt][nt] = z;

  // prologue: stage K-tile 0 into buffer 0 (8 loads/thread)
  #pragma unroll
  for (int s = 0; s < 4; ++s) {
    gld_lds16(Abase + soff[s], &As_[0][0] + (tid + 512 * s) * 16);
    gld_lds16(Bbase + soff[s], &Bs_[0][0] + (tid + 512 * s) * 16);
  }

  for (int t = 0; t < 16; ++t) {
    const int cur = t & 1;
    const unsigned char* Ab = &As_[cur][0];
    const unsigned char* Bb = &Bs_[cur][0];

    // issue ALL of next tile's staging up front (8 loads), then counted wait:
    // vmcnt(8) = everything from tile t has landed, t+1's 8 stay in flight
    // across the barrier (T4).
    if (t < 15) {
      unsigned char* An = &As_[cur ^ 1][0];
      unsigned char* Bn = &Bs_[cur ^ 1][0];
      const int kn = (t + 1) * 128;
      #pragma unroll
      for (int s = 0; s < 4; ++s) {
        gld_lds16(Abase + soff[s] + kn, An + (tid + 512 * s) * 16);
        gld_lds16(Bbase + soff[s] + kn, Bn + (tid + 512 * s) * 16);
      }
      asm volatile("s_waitcnt vmcnt(8)" ::: "memory");
    } else {
      asm volatile("s_waitcnt vmcnt(0)" ::: "memory");
    }
    asm volatile("s_barrier" ::: "memory");

    // ---- compute on buf[cur]: no barriers inside the tile ----
    // B fragments for the whole K-tile (32 VGPRs)
    intx8 bf[4];
    #pragma unroll
    for (int nt = 0; nt < 4; ++nt) {
      const int rb = wn * 64 + nt * 16 + rl;
      const int q0 = rb * 8 + ((2 * q) ^ sw);
      const int q1 = rb * 8 + ((2 * q + 1) ^ sw);
      bf[nt] = comb8(*(const intx4*)(Bb + q0 * 16),
                     *(const intx4*)(Bb + q1 * 16));
    }
    // A-fragment ping-pong, pipelined one sub-step ahead.
    intx8 af[2];
    {
      const int ra = wm * 128 + rl;
      const int a0 = ra * 8 + ((2 * q) ^ sw);
      const int a1 = ra * 8 + ((2 * q + 1) ^ sw);
      af[0] = comb8(*(const intx4*)(Ab + a0 * 16),
                    *(const intx4*)(Ab + a1 * 16));
    }
    #pragma unroll
    for (int s = 0; s < 8; ++s) {
      if (s < 7) {
        const int ra = wm * 128 + (s + 1) * 16 + rl;
        const int a0 = ra * 8 + ((2 * q) ^ sw);
        const int a1 = ra * 8 + ((2 * q + 1) ^ sw);
        af[(s + 1) & 1] = comb8(*(const intx4*)(Ab + a0 * 16),
                                *(const intx4*)(Ab + a1 * 16));
      }
      __builtin_amdgcn_s_setprio(1);
      #pragma unroll
      for (int nt = 0; nt < 4; ++nt)
        acc[s][nt] = __builtin_amdgcn_mfma_scale_f32_16x16x128_f8f6f4(
            af[s & 1], bf[nt], acc[s][nt],
            0, 0,            // cbsz = fp8(e4m3), blgp = fp8(e4m3)
            0, 127,          // scale A: 1.0
            0, 127);         // scale B: 1.0
      __builtin_amdgcn_s_setprio(0);
    }

    // end barrier: all waves done READING buf[cur] before t+1 stages into it
    asm volatile("s_barrier" ::: "memory");
  }

  // ---- epilogue. C/D layout: col = lane&15, row = (lane>>4)*4 + reg ----
  const int col0 = bx * BN + wn * 64 + rl;
  float hn[4], sc[4];
  #pragma unroll
  for (int nt = 0; nt < 4; ++nt) {
    hn[nt] = hneg[col0 + nt * 16];
    sc[nt] = isc[col0 + nt * 16];
  }
  const int row0 = by * BM + wm * 128 + (q << 2);

  // diag: rows wm*128.. overlap cols wn*64.. iff wm == wn>>1; row==col picks
  // mt = (wn&1)*4 + nt, q == rl>>2, reg rr == rl&3. ALL acc indices are
  // compile-time (rule #20); runtime selection lives in the store predicate.
  // atomicExch (device-scope) so the last block's reads see it across XCDs.
  if (bx == by && wm == (wn >> 1) && q == (rl >> 2)) {
    #pragma unroll
    for (int half = 0; half < 2; ++half) {
      #pragma unroll
      for (int nt = 0; nt < 4; ++nt) {
        #pragma unroll
        for (int rr = 0; rr < 4; ++rr) {
          if ((wn & 1) == half && (rl & 3) == rr)
            atomicExch(&diag[bx * BN + wn * 64 + nt * 16 + rl],
                       acc[half * 4 + nt][nt][rr] * sc[nt]);
        }
      }
    }
  }

  #pragma unroll
  for (int mt = 0; mt < 8; ++mt) {
    #pragma unroll
    for (int rr = 0; rr < 4; ++rr) {
      float p = 0.f;
      #pragma unroll
      for (int nt = 0; nt < 4; ++nt)
        p += __expf(INV_T * (acc[mt][nt][rr] * sc[nt] - hn[nt]));
      // reduce across 16 cols (lane&15 group)
      p += __shfl_xor(p, 1);
      p += __shfl_xor(p, 2);
      p += __shfl_xor(p, 4);
      p += __shfl_xor(p, 8);
      if (rl == 0)
        atomicAdd(&rowsum[row0 + mt * 16 + rr], p);
    }
  }

  // ---- fused finalize: last block to finish computes the loss ----
  __shared__ unsigned last_flag;
  __syncthreads();                         // all threads' atomics issued
  if (tid == 0) {
    __threadfence();                       // make them device-visible
    last_flag = (atomicAdd(cnt, 1u) == 255u);
  }
  __syncthreads();
  if (last_flag) {
    float c = 0.f;
    #pragma unroll
    for (int j = 0; j < 8; ++j) {
      const int i = tid + j * 512;
      c += __logf(rowsum[i]) - INV_T * (diag[i] - hneg[i]);
    }
    #pragma unroll
    for (int off = 32; off >= 1; off >>= 1) c += __shfl_xor(c, off);
    __shared__ float red[8];
    if (lane == 0) red[wave] = c;
    __syncthreads();
    if (tid == 0) {
      float tot = 0.f;
      #pragma unroll
      for (int w = 0; w < 8; ++w) tot += red[w];
      out[0] = tot * (1.0f / BATCH);
    }
  }
}

// ---------------------------------------------------------------------------
extern "C" void kernel_launch(void* const* d_in, const int* in_sizes, int n_in,
                              void* d_out, int out_size, void* d_ws, size_t ws_size,
                              hipStream_t stream) {
  const float* ci = (const float*)d_in[0];
  const float* cj = (const float*)d_in[1];
  float* out = (float*)d_out;

  // ws: Li8 u8[B*D] | Qb8 u8[B*D] | hneg f32[B] | isc f32[B] | rowsum f32[B]
  //     | diag f32[B] | cnt u32[1]
  unsigned char* Li8 = (unsigned char*)d_ws;
  unsigned char* Qb8 = Li8 + (size_t)BATCH * DIM;
  float* hneg   = (float*)(Qb8 + (size_t)BATCH * DIM);
  float* isc    = hneg + BATCH;
  float* rowsum = isc + BATCH;
  float* diag   = rowsum + BATCH;
  unsigned* cnt = (unsigned*)(diag + BATCH);

  prep_kernel<<<2 * BATCH / 4, 256, 0, stream>>>(ci, cj, Li8, Qb8, hneg, isc, rowsum, cnt);
  gemm_lse_kernel<<<(BATCH / BM) * (BATCH / BN), 512, 0, stream>>>(
      Li8, Qb8, hneg, isc, rowsum, diag, cnt, out);
}